// Round 5
// baseline (262.246 us; speedup 1.0000x reference)
//
#include <hip/hip_runtime.h>
#include <hip/hip_bf16.h>

// ---------------------------------------------------------------------------
// ClassicalSelfAttention: B=4, S=2048, D=1024, fp32 in/out.
// R5: mainloop switched to v_mfma_f32_32x32x16_bf16 (2x2 32x32 tiles/wave,
//     +15% MFMA pipe ceiling, half the issue slots, same LDS traffic);
//     grid orientation reverted to R3's measured-good x=row-tile-fast.
// Pipeline: prep (x->bf16, W->Wt^T bf16, bias concat, zero sums);
//   qkv (one 8192x3072 GEMM; Q,K -> d_out scratch, V -> Vt transposed);
//   scores (P=exp(qk/32-20) bf16 unnormalized + atomic row sums);
//   pv (out = (P@V)/sums).
// XOR-swizzled LDS staging via global_load_lds dwordx4 (0 bank conflicts).
// ---------------------------------------------------------------------------

using floatx16 = __attribute__((ext_vector_type(16))) float;
using shortx8  = __attribute__((ext_vector_type(8))) short;
using shortx4  = __attribute__((ext_vector_type(4))) short;

__device__ __forceinline__ short f2bf(float f) {
    __hip_bfloat16 h = __float2bfloat16(f);
    return *reinterpret_cast<short*>(&h);
}
__device__ __forceinline__ float bf2f(short s) {
    unsigned u = (unsigned)(unsigned short)s << 16;
    return __uint_as_float(u);
}

#define MFMA32(a, b, c) __builtin_amdgcn_mfma_f32_32x32x16_bf16((a), (b), (c), 0, 0, 0)

__device__ __forceinline__ void gld_lds16(const void* g, void* l) {
    __builtin_amdgcn_global_load_lds(
        (const __attribute__((address_space(1))) void*)g,
        (__attribute__((address_space(3))) void*)l, 16, 0, 0);
}

// ---------------------------------------------------------------------------
// GEMM mainloop: 128x128 tile, BK=64, 4 waves (2x2); each wave = 64x64 as
// 2x2 of 32x32x16 MFMAs. LDS [128][64] unpadded via global_load_lds dwordx4;
// XOR granule swizzle: LDS[r][c8] holds global granule c8^(r&7).
// A-frag: row m=lane&31, k=(lane>>5)*8+j.  C/D: col=lane&31,
// row=(reg&3)+8*(reg>>2)+4*(lane>>5)  [verified m74/m101].
// ---------------------------------------------------------------------------
__device__ __forceinline__ void gemm_loop(
    const short* __restrict__ A, const short* __restrict__ B,
    size_t lda, size_t ldb, int K,
    short* as_, short* bs_, floatx16 (&acc)[2][2], int w, int l)
{
    const int lr8 = l >> 3;
    const int swz = ((l & 7) ^ lr8) * 8;
    const int m31 = l & 31, hi = l >> 5, r8 = l & 7;
    const int wr = w >> 1, wc = w & 1;
    const short* pa = A + (size_t)(w * 32 + lr8) * lda + swz;
    const short* pb = B + (size_t)(w * 32 + lr8) * ldb + swz;
    short* la = as_ + w * 4 * 512;
    short* lb = bs_ + w * 4 * 512;

    for (int kt = 0; kt < K; kt += 64) {
        for (int c = 0; c < 4; ++c) {
            gld_lds16(pa + (size_t)c * 8 * lda + kt, la + c * 512);
            gld_lds16(pb + (size_t)c * 8 * ldb + kt, lb + c * 512);
        }
        __syncthreads();
        for (int kk = 0; kk < 64; kk += 16) {
            const int xg = (((kk >> 3) + hi) ^ r8) << 3;
            shortx8 af[2], bfr[2];
            for (int i = 0; i < 2; ++i)
                af[i] = *reinterpret_cast<const shortx8*>(
                    &as_[(size_t)(wr * 64 + i * 32 + m31) * 64 + xg]);
            for (int j = 0; j < 2; ++j)
                bfr[j] = *reinterpret_cast<const shortx8*>(
                    &bs_[(size_t)(wc * 64 + j * 32 + m31) * 64 + xg]);
            for (int i = 0; i < 2; ++i)
                for (int j = 0; j < 2; ++j)
                    acc[i][j] = MFMA32(af[i], bfr[j], acc[i][j]);
        }
        __syncthreads();
    }
}

// --------------------------------------------------------------------------
// prep: id<4096 xconv; id<4864 wconv 64x64 tile; id<4867 bias concat;
//       id<4875 zero sums.
// --------------------------------------------------------------------------
__global__ __launch_bounds__(256) void prep_kernel(
    const float* __restrict__ X,
    const float* __restrict__ Wq, const float* __restrict__ Wk,
    const float* __restrict__ Wv,
    const float* __restrict__ bq, const float* __restrict__ bk,
    const float* __restrict__ bv,
    short* __restrict__ Xb, short* __restrict__ Wt,
    float* __restrict__ bcat, float* __restrict__ sums)
{
    const int id = blockIdx.x, t = threadIdx.x;
    if (id < 4096) {
        size_t i = ((size_t)id * 256 + t) * 8;
        float4 v0 = *reinterpret_cast<const float4*>(X + i);
        float4 v1 = *reinterpret_cast<const float4*>(X + i + 4);
        shortx8 s;
        s[0] = f2bf(v0.x); s[1] = f2bf(v0.y); s[2] = f2bf(v0.z); s[3] = f2bf(v0.w);
        s[4] = f2bf(v1.x); s[5] = f2bf(v1.y); s[6] = f2bf(v1.z); s[7] = f2bf(v1.w);
        *reinterpret_cast<shortx8*>(Xb + i) = s;
    } else if (id < 4864) {
        __shared__ float tl[64][65];
        const int wid = id - 4096;
        const int z = wid >> 8, t16 = wid & 255;
        const float* src = (z == 0) ? Wq : (z == 1) ? Wk : Wv;
        short* dst = Wt + (size_t)z * 1024 * 1024;
        const int k0 = (t16 >> 4) * 64, n0 = (t16 & 15) * 64;
        for (int i = t; i < 64 * 64; i += 256) {
            int r = i >> 6, c = i & 63;
            tl[r][c] = src[(size_t)(k0 + r) * 1024 + n0 + c];
        }
        __syncthreads();
        for (int i = t; i < 64 * 64; i += 256) {
            int r = i >> 6, c = i & 63;
            dst[(size_t)(n0 + r) * 1024 + k0 + c] = f2bf(tl[c][r]);
        }
    } else if (id < 4867) {
        const int z = id - 4864;
        const float* bsrc = (z == 0) ? bq : (z == 1) ? bk : bv;
        for (int i = t; i < 1024; i += 256) bcat[z * 1024 + i] = bsrc[i];
    } else {
        const int sid = id - 4867;          // 0..7
        *reinterpret_cast<float4*>(&sums[sid * 1024 + t * 4]) =
            float4{0.f, 0.f, 0.f, 0.f};
    }
}

// --------------------------------------------------------------------------
// Fused QKV: C[8192][3072] = Xb @ Wt^T + bcat. Section by n0>>10:
//   0 -> dQ bf16 [8192][1024], 1 -> dK, 2 -> Vt [b][1024(d)][2048(s)].
// Grid (64, 24): x = m-tile fast (R3 orientation), y = n-tile.
// --------------------------------------------------------------------------
__global__ __launch_bounds__(256) void qkv_kernel(
    const short* __restrict__ Xb, const short* __restrict__ Wt,
    const float* __restrict__ bcat, short* __restrict__ dQ,
    short* __restrict__ dK, short* __restrict__ Vt)
{
    __shared__ short as_[128 * 64];
    __shared__ short bs_[128 * 64];
    const int t = threadIdx.x, w = t >> 6, l = t & 63;
    const int m0 = blockIdx.x * 128, n0 = blockIdx.y * 128;
    const int wr = w >> 1, wc = w & 1, m31 = l & 31, hi = l >> 5;
    const int sec = n0 >> 10;

    floatx16 acc[2][2];
    for (int i = 0; i < 2; ++i)
        for (int j = 0; j < 2; ++j)
            for (int r = 0; r < 16; ++r) acc[i][j][r] = 0.f;

    gemm_loop(Xb + (size_t)m0 * 1024, Wt + (size_t)n0 * 1024,
              1024, 1024, 1024, as_, bs_, acc, w, l);

    short* outN = (sec == 0) ? dQ : dK;
    for (int i = 0; i < 2; ++i) {
        for (int j = 0; j < 2; ++j) {
            int coln = n0 + wc * 64 + j * 32 + m31;    // 0..3071
            int col = coln & 1023;
            float bv = bcat[coln];
            for (int g = 0; g < 4; ++g) {
                int row = m0 + wr * 64 + i * 32 + g * 8 + hi * 4;
                if (sec < 2) {
                    for (int q = 0; q < 4; ++q)
                        outN[(size_t)(row + q) * 1024 + col] =
                            f2bf(acc[i][j][g * 4 + q] + bv);
                } else {
                    int b = row >> 11, sl = row & 2047;
                    shortx4 s;
                    for (int q = 0; q < 4; ++q) s[q] = f2bf(acc[i][j][g * 4 + q] + bv);
                    *reinterpret_cast<shortx4*>(
                        &Vt[((size_t)b * 1024 + col) * 2048 + sl]) = s;
                }
            }
        }
    }
}

// --------------------------------------------------------------------------
// P[m][key] = exp(q.k/32 - 20) bf16 (unnormalized) + atomic row partial sums
// over the SAME bf16-rounded values pv reads.
// Grid (rows/128, 16): x = q-row tile fast (R3 orientation), y = key tile.
// --------------------------------------------------------------------------
__global__ __launch_bounds__(256) void scores_kernel(
    const short* __restrict__ dQ, const short* __restrict__ dK,
    short* __restrict__ P, float* __restrict__ sums, int row_start)
{
    __shared__ short as_[128 * 64];
    __shared__ short bs_[128 * 64];
    const int t = threadIdx.x, w = t >> 6, l = t & 63;
    const int m0 = blockIdx.x * 128;          // chunk-local q rows
    const int n0 = blockIdx.y * 128;          // key tile
    const int g0 = row_start + m0;
    const int b = g0 >> 11;
    const int wr = w >> 1, wc = w & 1, m31 = l & 31, hi = l >> 5;

    floatx16 acc[2][2];
    for (int i = 0; i < 2; ++i)
        for (int j = 0; j < 2; ++j)
            for (int r = 0; r < 16; ++r) acc[i][j][r] = 0.f;

    gemm_loop(dQ + (size_t)g0 * 1024, dK + ((size_t)b * 2048 + n0) * 1024,
              1024, 1024, 1024, as_, bs_, acc, w, l);

    for (int i = 0; i < 2; ++i) {
        float rs[16];
        for (int r = 0; r < 16; ++r) rs[r] = 0.f;
        for (int j = 0; j < 2; ++j) {
            int col = n0 + wc * 64 + j * 32 + m31;
            for (int g = 0; g < 4; ++g) {
                int row = m0 + wr * 64 + i * 32 + g * 8 + hi * 4;
                for (int q = 0; q < 4; ++q) {
                    short pb = f2bf(__expf(acc[i][j][g * 4 + q] * 0.03125f - 20.0f));
                    P[(size_t)(row + q) * 2048 + col] = pb;
                    rs[g * 4 + q] += bf2f(pb);
                }
            }
        }
        // reduce across the 32 lanes sharing this row set (masks stay in half)
        for (int r = 0; r < 16; ++r)
            for (int m = 1; m <= 16; m <<= 1)
                rs[r] += __shfl_xor(rs[r], m, 64);
        if (m31 == 0) {
            for (int g = 0; g < 4; ++g) {
                int row = row_start + m0 + wr * 64 + i * 32 + g * 8 + hi * 4;
                for (int q = 0; q < 4; ++q)
                    atomicAdd(&sums[row + q], rs[g * 4 + q]);
            }
        }
    }
}

// --------------------------------------------------------------------------
// Out[row][d] = (P[m][:] @ V[b][:,d]) / sums[row].  Vt bf16 [b][d][key].
// Grid (rows/128, 8): x = row tile fast, y = d tile.
// --------------------------------------------------------------------------
__global__ __launch_bounds__(256) void pv_kernel(
    const short* __restrict__ P, const short* __restrict__ Vt,
    const float* __restrict__ sums, float* __restrict__ Out, int row_start)
{
    __shared__ short as_[128 * 64];
    __shared__ short bs_[128 * 64];
    const int t = threadIdx.x, w = t >> 6, l = t & 63;
    const int m0 = blockIdx.x * 128;          // chunk-local rows
    const int n0 = blockIdx.y * 128;          // d tile
    const int g0 = row_start + m0;
    const int b = g0 >> 11;
    const int wr = w >> 1, wc = w & 1, m31 = l & 31, hi = l >> 5;

    floatx16 acc[2][2];
    for (int i = 0; i < 2; ++i)
        for (int j = 0; j < 2; ++j)
            for (int r = 0; r < 16; ++r) acc[i][j][r] = 0.f;

    gemm_loop(P + (size_t)m0 * 2048, Vt + ((size_t)b * 1024 + n0) * 2048,
              2048, 2048, 2048, as_, bs_, acc, w, l);

    for (int i = 0; i < 2; ++i) {
        float is[16];
        for (int g = 0; g < 4; ++g) {
            int row = row_start + m0 + wr * 64 + i * 32 + g * 8 + hi * 4;
            float4 sv = *reinterpret_cast<const float4*>(&sums[row]);
            is[g * 4 + 0] = 1.0f / sv.x; is[g * 4 + 1] = 1.0f / sv.y;
            is[g * 4 + 2] = 1.0f / sv.z; is[g * 4 + 3] = 1.0f / sv.w;
        }
        for (int j = 0; j < 2; ++j) {
            int col = n0 + wc * 64 + j * 32 + m31;
            for (int g = 0; g < 4; ++g) {
                int row = row_start + m0 + wr * 64 + i * 32 + g * 8 + hi * 4;
                for (int q = 0; q < 4; ++q)
                    Out[(size_t)(row + q) * 1024 + col] =
                        acc[i][j][g * 4 + q] * is[g * 4 + q];
            }
        }
    }
}

// --------------------------------------------------------------------------
extern "C" void kernel_launch(void* const* d_in, const int* in_sizes, int n_in,
                              void* d_out, int out_size, void* d_ws, size_t ws_size,
                              hipStream_t stream)
{
    const float* x  = (const float*)d_in[0];
    const float* Wq = (const float*)d_in[1];
    const float* bq = (const float*)d_in[2];
    const float* Wk = (const float*)d_in[3];
    const float* bk = (const float*)d_in[4];
    const float* Wv = (const float*)d_in[5];
    const float* bv = (const float*)d_in[6];
    float* out = (float*)d_out;

    // d_out doubles as Q/K scratch (exactly 32 MiB): safe by stream ordering.
    short* dQ = (short*)d_out;
    short* dK = dQ + (size_t)8192 * 1024;

    char* ws = (char*)d_ws;
    short* Wt   = (short*)ws;                                 // 6 MiB
    float* bcat = (float*)(ws + 6291456);                     // 12 KiB
    float* sums = (float*)(ws + 6291456 + 12288);             // 32 KiB
    short* Vt   = (short*)(ws + 6291456 + 12288 + 32768);     // 16 MiB
    char*  region = ws + 6291456 + 12288 + 32768 + 16777216;  // P / Xb
    const size_t base = 6291456 + 12288 + 32768 + 16777216;   // ~22.05 MiB

    size_t avail = ws_size > base ? ws_size - base : 0;
    long rows_fit = (long)(avail / 4096);   // P row = 2048 bf16 = 4 KiB
    int chunk = (int)(rows_fit & ~127L);
    if (chunk > 8192) chunk = 8192;
    if (chunk < 128) chunk = 128;           // needs ws >= ~22.6 MiB
    short* Xb = (short*)region;             // 16 MiB, dead before P is written
    short* P  = (short*)region;

    prep_kernel<<<dim3(4875), 256, 0, stream>>>(x, Wq, Wk, Wv, bq, bk, bv,
                                                Xb, Wt, bcat, sums);
    qkv_kernel<<<dim3(64, 24), 256, 0, stream>>>(Xb, Wt, bcat, dQ, dK, Vt);

    for (int rs = 0; rs < 8192; rs += chunk) {
        int rows = 8192 - rs;
        if (rows > chunk) rows = chunk;
        scores_kernel<<<dim3(rows / 128, 16), 256, 0, stream>>>(dQ, dK, P, sums, rs);
        pv_kernel<<<dim3(rows / 128, 8), 256, 0, stream>>>(P, Vt, sums, out, rs);
    }
}

// Round 6
// 261.568 us; speedup vs baseline: 1.0026x; 1.0026x over previous
//
#include <hip/hip_runtime.h>
#include <hip/hip_bf16.h>

// ---------------------------------------------------------------------------
// ClassicalSelfAttention: B=4, S=2048, D=1024, fp32 in/out.
// R6: conflict-free swizzle for the 32x32x16 mainloop. R5's read pattern
// (granule base varies per 32-lane half) hit 6.29M bank conflicts; placement
// now adds a row-dependent rotation: LDS granule(row,g) =
// ((g + 2*((row>>4)&1))&7) ^ (row&7), making the read pattern match R3's
// verified conflict-free family (distinct granule base per 16-lane quad).
// Pipeline: prep; qkv (8192x3072, Q,K->d_out scratch, V->Vt transposed);
//   scores (P=exp(qk/32-20) bf16 unnormalized + atomic row sums);
//   pv (out = (P@V)/sums).
// ---------------------------------------------------------------------------

using floatx16 = __attribute__((ext_vector_type(16))) float;
using shortx8  = __attribute__((ext_vector_type(8))) short;
using shortx4  = __attribute__((ext_vector_type(4))) short;

__device__ __forceinline__ short f2bf(float f) {
    __hip_bfloat16 h = __float2bfloat16(f);
    return *reinterpret_cast<short*>(&h);
}
__device__ __forceinline__ float bf2f(short s) {
    unsigned u = (unsigned)(unsigned short)s << 16;
    return __uint_as_float(u);
}

#define MFMA32(a, b, c) __builtin_amdgcn_mfma_f32_32x32x16_bf16((a), (b), (c), 0, 0, 0)

__device__ __forceinline__ void gld_lds16(const void* g, void* l) {
    __builtin_amdgcn_global_load_lds(
        (const __attribute__((address_space(1))) void*)g,
        (__attribute__((address_space(3))) void*)l, 16, 0, 0);
}

// ---------------------------------------------------------------------------
// GEMM mainloop: 128x128 tile, BK=64, 4 waves (2x2); each wave = 64x64 as
// 2x2 of 32x32x16 MFMAs. LDS [128][64] unpadded via global_load_lds dwordx4.
// Swizzle: LDS granule(row,g) = ((g + 2*((row>>4)&1))&7) ^ (row&7).
// Write side: lane λ, chunk c stages row w*32+c*8+(λ>>3); (row>>4)&1 =
// (c>>1)&1, so fetch global granule ((λ&7)^(λ>>3) - 2*((c>>1)&1)) & 7.
// Read side: row = base + (l&31) with base ≡ 0 mod 32 -> (row>>4)&1 =
// (l>>4)&1; granule = (((kk>>3) + (l>>5) + 2*((l>>4)&1)) & 7) ^ (l&7).
// ---------------------------------------------------------------------------
__device__ __forceinline__ void gemm_loop(
    const short* __restrict__ A, const short* __restrict__ B,
    size_t lda, size_t ldb, int K,
    short* as_, short* bs_, floatx16 (&acc)[2][2], int w, int l)
{
    const int lr8 = l >> 3;
    const int bswz = (l & 7) ^ lr8;               // base write swizzle
    const int m31 = l & 31, hi = l >> 5, r8 = l & 7;
    const int rbit2 = (l >> 3) & 2;               // 2*((l>>4)&1)
    const int wr = w >> 1, wc = w & 1;
    const short* pa = A + (size_t)(w * 32 + lr8) * lda;
    const short* pb = B + (size_t)(w * 32 + lr8) * ldb;
    short* la = as_ + w * 4 * 512;
    short* lb = bs_ + w * 4 * 512;

    for (int kt = 0; kt < K; kt += 64) {
        for (int c = 0; c < 4; ++c) {
            const int gcol = ((bswz - (c & 2)) & 7) * 8;   // (c&2) == 2*((c>>1)&1)
            gld_lds16(pa + (size_t)c * 8 * lda + kt + gcol, la + c * 512);
            gld_lds16(pb + (size_t)c * 8 * ldb + kt + gcol, lb + c * 512);
        }
        __syncthreads();
        for (int kk = 0; kk < 64; kk += 16) {
            const int xg = ((((kk >> 3) + hi + rbit2) & 7) ^ r8) << 3;
            shortx8 af[2], bfr[2];
            for (int i = 0; i < 2; ++i)
                af[i] = *reinterpret_cast<const shortx8*>(
                    &as_[(size_t)(wr * 64 + i * 32 + m31) * 64 + xg]);
            for (int j = 0; j < 2; ++j)
                bfr[j] = *reinterpret_cast<const shortx8*>(
                    &bs_[(size_t)(wc * 64 + j * 32 + m31) * 64 + xg]);
            for (int i = 0; i < 2; ++i)
                for (int j = 0; j < 2; ++j)
                    acc[i][j] = MFMA32(af[i], bfr[j], acc[i][j]);
        }
        __syncthreads();
    }
}

// --------------------------------------------------------------------------
// prep: id<4096 xconv; id<4864 wconv 64x64 tile; id<4867 bias concat;
//       id<4875 zero sums.
// --------------------------------------------------------------------------
__global__ __launch_bounds__(256) void prep_kernel(
    const float* __restrict__ X,
    const float* __restrict__ Wq, const float* __restrict__ Wk,
    const float* __restrict__ Wv,
    const float* __restrict__ bq, const float* __restrict__ bk,
    const float* __restrict__ bv,
    short* __restrict__ Xb, short* __restrict__ Wt,
    float* __restrict__ bcat, float* __restrict__ sums)
{
    const int id = blockIdx.x, t = threadIdx.x;
    if (id < 4096) {
        size_t i = ((size_t)id * 256 + t) * 8;
        float4 v0 = *reinterpret_cast<const float4*>(X + i);
        float4 v1 = *reinterpret_cast<const float4*>(X + i + 4);
        shortx8 s;
        s[0] = f2bf(v0.x); s[1] = f2bf(v0.y); s[2] = f2bf(v0.z); s[3] = f2bf(v0.w);
        s[4] = f2bf(v1.x); s[5] = f2bf(v1.y); s[6] = f2bf(v1.z); s[7] = f2bf(v1.w);
        *reinterpret_cast<shortx8*>(Xb + i) = s;
    } else if (id < 4864) {
        __shared__ float tl[64][65];
        const int wid = id - 4096;
        const int z = wid >> 8, t16 = wid & 255;
        const float* src = (z == 0) ? Wq : (z == 1) ? Wk : Wv;
        short* dst = Wt + (size_t)z * 1024 * 1024;
        const int k0 = (t16 >> 4) * 64, n0 = (t16 & 15) * 64;
        for (int i = t; i < 64 * 64; i += 256) {
            int r = i >> 6, c = i & 63;
            tl[r][c] = src[(size_t)(k0 + r) * 1024 + n0 + c];
        }
        __syncthreads();
        for (int i = t; i < 64 * 64; i += 256) {
            int r = i >> 6, c = i & 63;
            dst[(size_t)(n0 + r) * 1024 + k0 + c] = f2bf(tl[c][r]);
        }
    } else if (id < 4867) {
        const int z = id - 4864;
        const float* bsrc = (z == 0) ? bq : (z == 1) ? bk : bv;
        for (int i = t; i < 1024; i += 256) bcat[z * 1024 + i] = bsrc[i];
    } else {
        const int sid = id - 4867;          // 0..7
        *reinterpret_cast<float4*>(&sums[sid * 1024 + t * 4]) =
            float4{0.f, 0.f, 0.f, 0.f};
    }
}

// --------------------------------------------------------------------------
// Fused QKV: C[8192][3072] = Xb @ Wt^T + bcat. Section by n0>>10:
//   0 -> dQ bf16 [8192][1024], 1 -> dK, 2 -> Vt [b][1024(d)][2048(s)].
// Grid (64, 24): x = m-tile fast, y = n-tile.
// --------------------------------------------------------------------------
__global__ __launch_bounds__(256) void qkv_kernel(
    const short* __restrict__ Xb, const short* __restrict__ Wt,
    const float* __restrict__ bcat, short* __restrict__ dQ,
    short* __restrict__ dK, short* __restrict__ Vt)
{
    __shared__ short as_[128 * 64];
    __shared__ short bs_[128 * 64];
    const int t = threadIdx.x, w = t >> 6, l = t & 63;
    const int m0 = blockIdx.x * 128, n0 = blockIdx.y * 128;
    const int wr = w >> 1, wc = w & 1, m31 = l & 31, hi = l >> 5;
    const int sec = n0 >> 10;

    floatx16 acc[2][2];
    for (int i = 0; i < 2; ++i)
        for (int j = 0; j < 2; ++j)
            for (int r = 0; r < 16; ++r) acc[i][j][r] = 0.f;

    gemm_loop(Xb + (size_t)m0 * 1024, Wt + (size_t)n0 * 1024,
              1024, 1024, 1024, as_, bs_, acc, w, l);

    short* outN = (sec == 0) ? dQ : dK;
    for (int i = 0; i < 2; ++i) {
        for (int j = 0; j < 2; ++j) {
            int coln = n0 + wc * 64 + j * 32 + m31;    // 0..3071
            int col = coln & 1023;
            float bv = bcat[coln];
            for (int g = 0; g < 4; ++g) {
                int row = m0 + wr * 64 + i * 32 + g * 8 + hi * 4;
                if (sec < 2) {
                    for (int q = 0; q < 4; ++q)
                        outN[(size_t)(row + q) * 1024 + col] =
                            f2bf(acc[i][j][g * 4 + q] + bv);
                } else {
                    int b = row >> 11, sl = row & 2047;
                    shortx4 s;
                    for (int q = 0; q < 4; ++q) s[q] = f2bf(acc[i][j][g * 4 + q] + bv);
                    *reinterpret_cast<shortx4*>(
                        &Vt[((size_t)b * 1024 + col) * 2048 + sl]) = s;
                }
            }
        }
    }
}

// --------------------------------------------------------------------------
// P[m][key] = exp(q.k/32 - 20) bf16 (unnormalized) + atomic row partial sums
// over the SAME bf16-rounded values pv reads.
// Grid (rows/128, 16): x = q-row tile fast, y = key tile.
// --------------------------------------------------------------------------
__global__ __launch_bounds__(256) void scores_kernel(
    const short* __restrict__ dQ, const short* __restrict__ dK,
    short* __restrict__ P, float* __restrict__ sums, int row_start)
{
    __shared__ short as_[128 * 64];
    __shared__ short bs_[128 * 64];
    const int t = threadIdx.x, w = t >> 6, l = t & 63;
    const int m0 = blockIdx.x * 128;          // chunk-local q rows
    const int n0 = blockIdx.y * 128;          // key tile
    const int g0 = row_start + m0;
    const int b = g0 >> 11;
    const int wr = w >> 1, wc = w & 1, m31 = l & 31, hi = l >> 5;

    floatx16 acc[2][2];
    for (int i = 0; i < 2; ++i)
        for (int j = 0; j < 2; ++j)
            for (int r = 0; r < 16; ++r) acc[i][j][r] = 0.f;

    gemm_loop(dQ + (size_t)g0 * 1024, dK + ((size_t)b * 2048 + n0) * 1024,
              1024, 1024, 1024, as_, bs_, acc, w, l);

    for (int i = 0; i < 2; ++i) {
        float rs[16];
        for (int r = 0; r < 16; ++r) rs[r] = 0.f;
        for (int j = 0; j < 2; ++j) {
            int col = n0 + wc * 64 + j * 32 + m31;
            for (int g = 0; g < 4; ++g) {
                int row = m0 + wr * 64 + i * 32 + g * 8 + hi * 4;
                for (int q = 0; q < 4; ++q) {
                    short pb = f2bf(__expf(acc[i][j][g * 4 + q] * 0.03125f - 20.0f));
                    P[(size_t)(row + q) * 2048 + col] = pb;
                    rs[g * 4 + q] += bf2f(pb);
                }
            }
        }
        for (int r = 0; r < 16; ++r)
            for (int m = 1; m <= 16; m <<= 1)
                rs[r] += __shfl_xor(rs[r], m, 64);
        if (m31 == 0) {
            for (int g = 0; g < 4; ++g) {
                int row = row_start + m0 + wr * 64 + i * 32 + g * 8 + hi * 4;
                for (int q = 0; q < 4; ++q)
                    atomicAdd(&sums[row + q], rs[g * 4 + q]);
            }
        }
    }
}

// --------------------------------------------------------------------------
// Out[row][d] = (P[m][:] @ V[b][:,d]) / sums[row].  Vt bf16 [b][d][key].
// Grid (rows/128, 8): x = row tile fast, y = d tile.
// --------------------------------------------------------------------------
__global__ __launch_bounds__(256) void pv_kernel(
    const short* __restrict__ P, const short* __restrict__ Vt,
    const float* __restrict__ sums, float* __restrict__ Out, int row_start)
{
    __shared__ short as_[128 * 64];
    __shared__ short bs_[128 * 64];
    const int t = threadIdx.x, w = t >> 6, l = t & 63;
    const int m0 = blockIdx.x * 128;          // chunk-local rows
    const int n0 = blockIdx.y * 128;          // d tile
    const int g0 = row_start + m0;
    const int b = g0 >> 11;
    const int wr = w >> 1, wc = w & 1, m31 = l & 31, hi = l >> 5;

    floatx16 acc[2][2];
    for (int i = 0; i < 2; ++i)
        for (int j = 0; j < 2; ++j)
            for (int r = 0; r < 16; ++r) acc[i][j][r] = 0.f;

    gemm_loop(P + (size_t)m0 * 2048, Vt + ((size_t)b * 1024 + n0) * 2048,
              2048, 2048, 2048, as_, bs_, acc, w, l);

    for (int i = 0; i < 2; ++i) {
        float is[16];
        for (int g = 0; g < 4; ++g) {
            int row = row_start + m0 + wr * 64 + i * 32 + g * 8 + hi * 4;
            float4 sv = *reinterpret_cast<const float4*>(&sums[row]);
            is[g * 4 + 0] = 1.0f / sv.x; is[g * 4 + 1] = 1.0f / sv.y;
            is[g * 4 + 2] = 1.0f / sv.z; is[g * 4 + 3] = 1.0f / sv.w;
        }
        for (int j = 0; j < 2; ++j) {
            int col = n0 + wc * 64 + j * 32 + m31;
            for (int g = 0; g < 4; ++g) {
                int row = row_start + m0 + wr * 64 + i * 32 + g * 8 + hi * 4;
                for (int q = 0; q < 4; ++q)
                    Out[(size_t)(row + q) * 1024 + col] =
                        acc[i][j][g * 4 + q] * is[g * 4 + q];
            }
        }
    }
}

// --------------------------------------------------------------------------
extern "C" void kernel_launch(void* const* d_in, const int* in_sizes, int n_in,
                              void* d_out, int out_size, void* d_ws, size_t ws_size,
                              hipStream_t stream)
{
    const float* x  = (const float*)d_in[0];
    const float* Wq = (const float*)d_in[1];
    const float* bq = (const float*)d_in[2];
    const float* Wk = (const float*)d_in[3];
    const float* bk = (const float*)d_in[4];
    const float* Wv = (const float*)d_in[5];
    const float* bv = (const float*)d_in[6];
    float* out = (float*)d_out;

    // d_out doubles as Q/K scratch (exactly 32 MiB): safe by stream ordering.
    short* dQ = (short*)d_out;
    short* dK = dQ + (size_t)8192 * 1024;

    char* ws = (char*)d_ws;
    short* Wt   = (short*)ws;                                 // 6 MiB
    float* bcat = (float*)(ws + 6291456);                     // 12 KiB
    float* sums = (float*)(ws + 6291456 + 12288);             // 32 KiB
    short* Vt   = (short*)(ws + 6291456 + 12288 + 32768);     // 16 MiB
    char*  region = ws + 6291456 + 12288 + 32768 + 16777216;  // P / Xb
    const size_t base = 6291456 + 12288 + 32768 + 16777216;   // ~22.05 MiB

    size_t avail = ws_size > base ? ws_size - base : 0;
    long rows_fit = (long)(avail / 4096);   // P row = 2048 bf16 = 4 KiB
    int chunk = (int)(rows_fit & ~127L);
    if (chunk > 8192) chunk = 8192;
    if (chunk < 128) chunk = 128;           // needs ws >= ~22.6 MiB
    short* Xb = (short*)region;             // 16 MiB, dead before P is written
    short* P  = (short*)region;

    prep_kernel<<<dim3(4875), 256, 0, stream>>>(x, Wq, Wk, Wv, bq, bk, bv,
                                                Xb, Wt, bcat, sums);
    qkv_kernel<<<dim3(64, 24), 256, 0, stream>>>(Xb, Wt, bcat, dQ, dK, Vt);

    for (int rs = 0; rs < 8192; rs += chunk) {
        int rows = 8192 - rs;
        if (rows > chunk) rows = chunk;
        scores_kernel<<<dim3(rows / 128, 16), 256, 0, stream>>>(dQ, dK, P, sums, rs);
        pv_kernel<<<dim3(rows / 128, 8), 256, 0, stream>>>(P, Vt, sums, out, rs);
    }
}

// Round 7
// 241.416 us; speedup vs baseline: 1.0863x; 1.0835x over previous
//
#include <hip/hip_runtime.h>
#include <hip/hip_bf16.h>

// ---------------------------------------------------------------------------
// ClassicalSelfAttention: B=4, S=2048, D=1024, fp32 in/out.
// R7: consolidation round. 16x16 mainloop (R3-verified: 0 bank conflicts,
// scores 47.4us) + qkv m-fast grid (R5-verified: FETCH 77->41.5MB) +
// scores/pv row-fast grids (R3-verified orientation). The 32x32 mainloop
// (R5/R6) carries a fixed 6.29M-cycle LDS tax that two different swizzles
// could not remove -- reverted.
// Pipeline: prep; qkv (8192x3072, Q,K->d_out scratch, V->Vt transposed);
//   scores (P=exp(qk/32-20) bf16 unnormalized + atomic row sums);
//   pv (out = (P@V)/sums).
// ---------------------------------------------------------------------------

using floatx4 = __attribute__((ext_vector_type(4))) float;
using shortx8 = __attribute__((ext_vector_type(8))) short;
using shortx4 = __attribute__((ext_vector_type(4))) short;

__device__ __forceinline__ short f2bf(float f) {
    __hip_bfloat16 h = __float2bfloat16(f);
    return *reinterpret_cast<short*>(&h);
}
__device__ __forceinline__ float bf2f(short s) {
    unsigned u = (unsigned)(unsigned short)s << 16;
    return __uint_as_float(u);
}

#define MFMA16(a, b, c) __builtin_amdgcn_mfma_f32_16x16x32_bf16((a), (b), (c), 0, 0, 0)

__device__ __forceinline__ void gld_lds16(const void* g, void* l) {
    __builtin_amdgcn_global_load_lds(
        (const __attribute__((address_space(1))) void*)g,
        (__attribute__((address_space(3))) void*)l, 16, 0, 0);
}

// ---------------------------------------------------------------------------
// GEMM mainloop (R3/R4, measured 0 conflicts): 128x128 tile, BK=64, 4 waves
// (2x2), each wave 4x4 of 16x16x32 MFMAs. LDS [128][64] unpadded via
// global_load_lds dwordx4. XOR granule swizzle: LDS[r][c8] holds global
// granule c8^(r&7); reads use granule g at position g^(row&7).
// ---------------------------------------------------------------------------
__device__ __forceinline__ void gemm_loop(
    const short* __restrict__ A, const short* __restrict__ B,
    size_t lda, size_t ldb, int K,
    short* as_, short* bs_, floatx4 (&acc)[4][4], int w, int l)
{
    const int lr8 = l >> 3;
    const int swz = ((l & 7) ^ lr8) * 8;
    const int lrow = l & 15, quad = l >> 4;
    const int wr = w >> 1, wc = w & 1;
    const int r8r = lrow & 7;
    const short* pa = A + (size_t)(w * 32 + lr8) * lda + swz;
    const short* pb = B + (size_t)(w * 32 + lr8) * ldb + swz;
    short* la = as_ + w * 4 * 512;
    short* lb = bs_ + w * 4 * 512;

    for (int kt = 0; kt < K; kt += 64) {
        for (int c = 0; c < 4; ++c) {
            gld_lds16(pa + (size_t)c * 8 * lda + kt, la + c * 512);
            gld_lds16(pb + (size_t)c * 8 * ldb + kt, lb + c * 512);
        }
        __syncthreads();
        for (int kk = 0; kk < 64; kk += 32) {
            const int xoff = (((kk >> 3) + quad) ^ r8r) << 3;
            shortx8 af[4], bfr[4];
            for (int i = 0; i < 4; ++i)
                af[i] = *reinterpret_cast<const shortx8*>(
                    &as_[(size_t)(wr * 64 + i * 16 + lrow) * 64 + xoff]);
            for (int j = 0; j < 4; ++j)
                bfr[j] = *reinterpret_cast<const shortx8*>(
                    &bs_[(size_t)(wc * 64 + j * 16 + lrow) * 64 + xoff]);
            for (int i = 0; i < 4; ++i)
                for (int j = 0; j < 4; ++j)
                    acc[i][j] = MFMA16(af[i], bfr[j], acc[i][j]);
        }
        __syncthreads();
    }
}

// --------------------------------------------------------------------------
// prep: id<4096 xconv; id<4864 wconv 64x64 tile; id<4867 bias concat;
//       id<4875 zero sums.
// --------------------------------------------------------------------------
__global__ __launch_bounds__(256) void prep_kernel(
    const float* __restrict__ X,
    const float* __restrict__ Wq, const float* __restrict__ Wk,
    const float* __restrict__ Wv,
    const float* __restrict__ bq, const float* __restrict__ bk,
    const float* __restrict__ bv,
    short* __restrict__ Xb, short* __restrict__ Wt,
    float* __restrict__ bcat, float* __restrict__ sums)
{
    const int id = blockIdx.x, t = threadIdx.x;
    if (id < 4096) {
        size_t i = ((size_t)id * 256 + t) * 8;
        float4 v0 = *reinterpret_cast<const float4*>(X + i);
        float4 v1 = *reinterpret_cast<const float4*>(X + i + 4);
        shortx8 s;
        s[0] = f2bf(v0.x); s[1] = f2bf(v0.y); s[2] = f2bf(v0.z); s[3] = f2bf(v0.w);
        s[4] = f2bf(v1.x); s[5] = f2bf(v1.y); s[6] = f2bf(v1.z); s[7] = f2bf(v1.w);
        *reinterpret_cast<shortx8*>(Xb + i) = s;
    } else if (id < 4864) {
        __shared__ float tl[64][65];
        const int wid = id - 4096;
        const int z = wid >> 8, t16 = wid & 255;
        const float* src = (z == 0) ? Wq : (z == 1) ? Wk : Wv;
        short* dst = Wt + (size_t)z * 1024 * 1024;
        const int k0 = (t16 >> 4) * 64, n0 = (t16 & 15) * 64;
        for (int i = t; i < 64 * 64; i += 256) {
            int r = i >> 6, c = i & 63;
            tl[r][c] = src[(size_t)(k0 + r) * 1024 + n0 + c];
        }
        __syncthreads();
        for (int i = t; i < 64 * 64; i += 256) {
            int r = i >> 6, c = i & 63;
            dst[(size_t)(n0 + r) * 1024 + k0 + c] = f2bf(tl[c][r]);
        }
    } else if (id < 4867) {
        const int z = id - 4864;
        const float* bsrc = (z == 0) ? bq : (z == 1) ? bk : bv;
        for (int i = t; i < 1024; i += 256) bcat[z * 1024 + i] = bsrc[i];
    } else {
        const int sid = id - 4867;          // 0..7
        *reinterpret_cast<float4*>(&sums[sid * 1024 + t * 4]) =
            float4{0.f, 0.f, 0.f, 0.f};
    }
}

// --------------------------------------------------------------------------
// Fused QKV: C[8192][3072] = Xb @ Wt^T + bcat. Section by n0>>10:
//   0 -> dQ bf16 [8192][1024], 1 -> dK, 2 -> Vt [b][1024(d)][2048(s)].
// Grid (64, 24): x = m-tile fast (R5/R6-measured FETCH win), y = n-tile.
// --------------------------------------------------------------------------
__global__ __launch_bounds__(256) void qkv_kernel(
    const short* __restrict__ Xb, const short* __restrict__ Wt,
    const float* __restrict__ bcat, short* __restrict__ dQ,
    short* __restrict__ dK, short* __restrict__ Vt)
{
    __shared__ short as_[128 * 64];
    __shared__ short bs_[128 * 64];
    const int t = threadIdx.x, w = t >> 6, l = t & 63;
    const int m0 = blockIdx.x * 128, n0 = blockIdx.y * 128;
    const int wr = w >> 1, wc = w & 1, lrow = l & 15, quad = l >> 4;
    const int sec = n0 >> 10;

    floatx4 acc[4][4];
    for (int i = 0; i < 4; ++i)
        for (int j = 0; j < 4; ++j) acc[i][j] = floatx4{0.f, 0.f, 0.f, 0.f};

    gemm_loop(Xb + (size_t)m0 * 1024, Wt + (size_t)n0 * 1024,
              1024, 1024, 1024, as_, bs_, acc, w, l);

    short* outN = (sec == 0) ? dQ : dK;
    for (int i = 0; i < 4; ++i) {
        int rbase = m0 + wr * 64 + i * 16 + quad * 4;
        for (int j = 0; j < 4; ++j) {
            int coln = n0 + wc * 64 + j * 16 + lrow;   // 0..3071
            int col = coln & 1023;
            float bv = bcat[coln];
            if (sec < 2) {
                for (int r = 0; r < 4; ++r)
                    outN[(size_t)(rbase + r) * 1024 + col] =
                        f2bf(acc[i][j][r] + bv);
            } else {
                int b = rbase >> 11, sl = rbase & 2047;
                shortx4 s;
                for (int r = 0; r < 4; ++r) s[r] = f2bf(acc[i][j][r] + bv);
                *reinterpret_cast<shortx4*>(
                    &Vt[((size_t)b * 1024 + col) * 2048 + sl]) = s;
            }
        }
    }
}

// --------------------------------------------------------------------------
// P[m][key] = exp(q.k/32 - 20) bf16 (unnormalized) + atomic row partial sums
// over the SAME bf16-rounded values pv reads.
// Grid (rows/128, 16): x = q-row tile fast (R3-measured 47.4us), y = key tile.
// --------------------------------------------------------------------------
__global__ __launch_bounds__(256) void scores_kernel(
    const short* __restrict__ dQ, const short* __restrict__ dK,
    short* __restrict__ P, float* __restrict__ sums, int row_start)
{
    __shared__ short as_[128 * 64];
    __shared__ short bs_[128 * 64];
    const int t = threadIdx.x, w = t >> 6, l = t & 63;
    const int m0 = blockIdx.x * 128;          // chunk-local q rows
    const int n0 = blockIdx.y * 128;          // key tile
    const int g0 = row_start + m0;
    const int b = g0 >> 11;
    const int wr = w >> 1, wc = w & 1, lrow = l & 15, quad = l >> 4;

    floatx4 acc[4][4];
    for (int i = 0; i < 4; ++i)
        for (int j = 0; j < 4; ++j) acc[i][j] = floatx4{0.f, 0.f, 0.f, 0.f};

    gemm_loop(dQ + (size_t)g0 * 1024, dK + ((size_t)b * 2048 + n0) * 1024,
              1024, 1024, 1024, as_, bs_, acc, w, l);

    for (int i = 0; i < 4; ++i) {
        int rloc = m0 + wr * 64 + i * 16 + quad * 4;
        float rs[4] = {0.f, 0.f, 0.f, 0.f};
        for (int j = 0; j < 4; ++j) {
            int col = n0 + wc * 64 + j * 16 + lrow;
            for (int r = 0; r < 4; ++r) {
                short pb = f2bf(__expf(acc[i][j][r] * 0.03125f - 20.0f));
                P[(size_t)(rloc + r) * 2048 + col] = pb;
                rs[r] += bf2f(pb);
            }
        }
        for (int r = 0; r < 4; ++r)
            for (int m = 1; m <= 8; m <<= 1)
                rs[r] += __shfl_xor(rs[r], m, 64);
        if (lrow == 0)
            for (int r = 0; r < 4; ++r)
                atomicAdd(&sums[row_start + rloc + r], rs[r]);
    }
}

// --------------------------------------------------------------------------
// Out[row][d] = (P[m][:] @ V[b][:,d]) / sums[row].  Vt bf16 [b][d][key].
// Grid (rows/128, 8): x = row tile fast, y = d tile.
// --------------------------------------------------------------------------
__global__ __launch_bounds__(256) void pv_kernel(
    const short* __restrict__ P, const short* __restrict__ Vt,
    const float* __restrict__ sums, float* __restrict__ Out, int row_start)
{
    __shared__ short as_[128 * 64];
    __shared__ short bs_[128 * 64];
    const int t = threadIdx.x, w = t >> 6, l = t & 63;
    const int m0 = blockIdx.x * 128;          // chunk-local rows
    const int n0 = blockIdx.y * 128;          // d tile
    const int g0 = row_start + m0;
    const int b = g0 >> 11;
    const int wr = w >> 1, wc = w & 1, lrow = l & 15, quad = l >> 4;

    floatx4 acc[4][4];
    for (int i = 0; i < 4; ++i)
        for (int j = 0; j < 4; ++j) acc[i][j] = floatx4{0.f, 0.f, 0.f, 0.f};

    gemm_loop(P + (size_t)m0 * 2048, Vt + ((size_t)b * 1024 + n0) * 2048,
              2048, 2048, 2048, as_, bs_, acc, w, l);

    for (int i = 0; i < 4; ++i) {
        int rloc = m0 + wr * 64 + i * 16 + quad * 4;
        int rglb = row_start + rloc;
        float is[4];
        for (int r = 0; r < 4; ++r) is[r] = 1.0f / sums[rglb + r];
        for (int j = 0; j < 4; ++j) {
            int col = n0 + wc * 64 + j * 16 + lrow;
            for (int r = 0; r < 4; ++r)
                Out[(size_t)(rglb + r) * 1024 + col] = acc[i][j][r] * is[r];
        }
    }
}

// --------------------------------------------------------------------------
extern "C" void kernel_launch(void* const* d_in, const int* in_sizes, int n_in,
                              void* d_out, int out_size, void* d_ws, size_t ws_size,
                              hipStream_t stream)
{
    const float* x  = (const float*)d_in[0];
    const float* Wq = (const float*)d_in[1];
    const float* bq = (const float*)d_in[2];
    const float* Wk = (const float*)d_in[3];
    const float* bk = (const float*)d_in[4];
    const float* Wv = (const float*)d_in[5];
    const float* bv = (const float*)d_in[6];
    float* out = (float*)d_out;

    // d_out doubles as Q/K scratch (exactly 32 MiB): safe by stream ordering.
    short* dQ = (short*)d_out;
    short* dK = dQ + (size_t)8192 * 1024;

    char* ws = (char*)d_ws;
    short* Wt   = (short*)ws;                                 // 6 MiB
    float* bcat = (float*)(ws + 6291456);                     // 12 KiB
    float* sums = (float*)(ws + 6291456 + 12288);             // 32 KiB
    short* Vt   = (short*)(ws + 6291456 + 12288 + 32768);     // 16 MiB
    char*  region = ws + 6291456 + 12288 + 32768 + 16777216;  // P / Xb
    const size_t base = 6291456 + 12288 + 32768 + 16777216;   // ~22.05 MiB

    size_t avail = ws_size > base ? ws_size - base : 0;
    long rows_fit = (long)(avail / 4096);   // P row = 2048 bf16 = 4 KiB
    int chunk = (int)(rows_fit & ~127L);
    if (chunk > 8192) chunk = 8192;
    if (chunk < 128) chunk = 128;           // needs ws >= ~22.6 MiB
    short* Xb = (short*)region;             // 16 MiB, dead before P is written
    short* P  = (short*)region;

    prep_kernel<<<dim3(4875), 256, 0, stream>>>(x, Wq, Wk, Wv, bq, bk, bv,
                                                Xb, Wt, bcat, sums);
    qkv_kernel<<<dim3(64, 24), 256, 0, stream>>>(Xb, Wt, bcat, dQ, dK, Vt);

    for (int rs = 0; rs < 8192; rs += chunk) {
        int rows = 8192 - rs;
        if (rows > chunk) rows = chunk;
        scores_kernel<<<dim3(rows / 128, 16), 256, 0, stream>>>(dQ, dK, P, sums, rs);
        pv_kernel<<<dim3(rows / 128, 8), 256, 0, stream>>>(P, Vt, sums, out, rs);
    }
}